// Round 6
// baseline (254.307 us; speedup 1.0000x reference)
//
#include <hip/hip_runtime.h>

// GraphConstruction: x[1,1024,1024] fp32 -> A[4096,4096] in {0,1} fp32.
// patches[n,r,k] = x[h,w], h = (n&15)*64 + (r>>2)*16 + (n>>8),
//                          w = (r&3)*256 + k*16 + ((n>>4)&15)
// LOCKED NUMERICS (R6..R18, absmax 0):
//   sq[n,k]: acc = p0^2; acc = acc + fl(p_r^2), r ascending (plain adds)
//   G: acc = fmaf(a_r, b_r, acc), r ascending;  d2 = fmaf(-2,G,fl(si+sj))
//   decision: all_k (d2 <= 49.0f) == !any_k (d2 > 49.0f) -> per-cell FAIL
//   BIT. A bit-exactly symmetric -> mirror stores.
// R19: 512-thread block (8 waves), 128x128 tile, 8x4 per-thread.
//   R17/R18 post-mortem: with 256-thread blocks at 204 VGPR + 38.9KB LDS,
//   runtime residency is 1 wave/SIMD NO MATTER the waves_per_eu max
//   ((1,1) and (1,2) identical: Occ 8%, VALUBusy 42%, dur 188us = 2
//   sequential 96us blocks/CU). Multi-BLOCK co-residency is gated by
//   something source-invisible. Fix: intra-block residency — 512 threads
//   = 2 waves/SIMD guaranteed co-resident (same workgroup). Per-thread
//   8x4 tile: live = d(32)+a(32)+b(16)+addr ~110-130 VGPR; x2 waves fits
//   every pool model. LDS economics 1.5 B/FMA (R13=2.0, R18=1.0).
//   Attr stays (1,2): min=1 is the empirically-proven no-spill budget
//   (R17/R18: VGPR 200/204, WRITE=65.5MB pure output).
//   Diagnostics: VGPR 110-150 & WRITE ~65.5MB (no respill), Occ ~14-20%,
//   VALUBusy 60-78%, dur 75-100us.

#define NPATCH 4096
#define BT 128
#define NT (NPATCH / BT)   // 32 -> 528 lower-triangle blocks
#define NPH 8
#define KC 2
#define RSTRIDE 9          // float4 per row (8 data chunks + 1 pad)

__device__ __forceinline__ int swzrow(int row) {
    return ((row >> 2) + (row >> 5)) & 7;
}

// dot-accumulate: components x..w = r ascending (locked chain)
#define DOT(dst, av, bv)               \
    dst = fmaf(av.x, bv.x, dst);       \
    dst = fmaf(av.y, bv.y, dst);       \
    dst = fmaf(av.z, bv.z, dst);       \
    dst = fmaf(av.w, bv.w, dst);

#define LDA(u)                                                                 \
    const float4 a##u = Si[(ty * 8 + u) * RSTRIDE +                            \
                           (c ^ ((((ty * 8 + u) >> 2) + ((ty * 8 + u) >> 5)) & 7))];

#define LDB(v)                                                                 \
    const float4 b##v = Sj[(tx * 4 + v) * RSTRIDE +                            \
                           (c ^ ((((tx * 4 + v) >> 2) + ((tx * 4 + v) >> 5)) & 7))];

// d{u} = float4 over the 4 columns v=0..3
#define ROWU(u)                \
    DOT(d##u.x, a##u, b0)      \
    DOT(d##u.y, a##u, b1)      \
    DOT(d##u.z, a##u, b2)      \
    DOT(d##u.w, a##u, b3)

#define CELLX(dv, siv, sjv, bit)                                               \
    {                                                                          \
        const float s_ = (siv) + (sjv);           /* fl(si+sj) */              \
        const float d2_ = fmaf(-2.0f, dv, s_);    /* fl(s-2G)  */              \
        fail |= (d2_ > 49.0f ? 1u : 0u) << (bit);                              \
    }

#define EPIROW(u, siv)                         \
    CELLX(d##u.x, siv, sj4.x, (u) * 4 + 0)     \
    CELLX(d##u.y, siv, sj4.y, (u) * 4 + 1)     \
    CELLX(d##u.z, siv, sj4.z, (u) * 4 + 2)     \
    CELLX(d##u.w, siv, sj4.w, (u) * 4 + 3)

__global__ __launch_bounds__(512)
__attribute__((amdgpu_waves_per_eu(1, 2)))
void adj_kernel(const float* __restrict__ x, float* __restrict__ A) {
#pragma clang fp contract(off)
    __shared__ float4 Si[BT * RSTRIDE];
    __shared__ float4 Sj[BT * RSTRIDE];
    __shared__ float sqs[2][KC][BT];

    // linear -> lower-triangle (bi >= bj)
    int t = blockIdx.x;
    int bi = (int)((sqrtf(8.0f * (float)t + 1.0f) - 1.0f) * 0.5f);
    while ((bi + 1) * (bi + 2) / 2 <= t) ++bi;
    while (bi * (bi + 1) / 2 > t) --bi;
    int bj = t - bi * (bi + 1) / 2;

    const int i0 = bi * BT;
    const int j0 = bj * BT;
    const int tid = threadIdx.x;
    const int tx = tid & 31;       // j-cols tx*4..+3
    const int ty = tid >> 5;       // i-rows ty*8..+7

    unsigned fail = 0u;            // bit u*4+v, u<8, v<4

    for (int kp = 0; kp < NPH; ++kp) {
        __syncthreads();
        // ---- stage: 2048 float4 loads, 4/thread; each covers 4 rows ----
#pragma unroll
        for (int l = 0; l < 4; ++l) {
            int gid = l * 512 + tid;
            int side = gid >> 10;
            int q = gid & 1023;            // m4(4) | r(4) | kl(1) | g(1)
            int g = q & 1;
            int kl = (q >> 1) & 1;
            int r = (q >> 2) & 15;
            int m4 = q >> 6;
            int k = kp * KC + kl;
            int bt = side ? bj : bi;
            int h = m4 * 64 + (r >> 2) * 16 + (bt >> 1);
            int w0 = (r & 3) * 256 + k * 16 + 8 * (bt & 1) + 4 * g;
            float4 v = *(const float4*)&x[h * 1024 + w0];
            int c = (kl << 2) | (r >> 2);
            int e = r & 3;
            float* Sb = side ? (float*)Sj : (float*)Si;
#pragma unroll
            for (int dd = 0; dd < 4; ++dd) {   // elem dd -> row (4g+dd)*16+m4
                float val = (dd == 0) ? v.x : (dd == 1) ? v.y : (dd == 2) ? v.z : v.w;
                int row = (4 * g + dd) * 16 + m4;
                int ch = c ^ swzrow(row);
                Sb[(row * RSTRIDE + ch) * 4 + e] = val;
            }
        }
        __syncthreads();
        // ---- per-column sq: plain adds, r ascending (1 value/thread) ----
        {
            int side = tid >> 8;
            int kl = (tid >> 7) & 1;
            int row = tid & 127;
            const float4* Sb = (side ? Sj : Si) + row * RSTRIDE;
            int swz = swzrow(row);
            float acc;
            {
                float4 v = Sb[(kl * 4) ^ swz];
                acc = v.x * v.x;
                float t1 = v.y * v.y; acc = acc + t1;
                float t2 = v.z * v.z; acc = acc + t2;
                float t3 = v.w * v.w; acc = acc + t3;
            }
#pragma unroll
            for (int rc = 1; rc < 4; ++rc) {
                float4 v = Sb[(kl * 4 + rc) ^ swz];
                float t0 = v.x * v.x; acc = acc + t0;
                float t1 = v.y * v.y; acc = acc + t1;
                float t2 = v.z * v.z; acc = acc + t2;
                float t3 = v.w * v.w; acc = acc + t3;
            }
            sqs[side][kl][row] = acc;
        }
        __syncthreads();
        // ---- compute: 8x4 cells via named float4 accumulators ----
#pragma unroll
        for (int kl = 0; kl < KC; ++kl) {
            float4 d0 = {0.f, 0.f, 0.f, 0.f}, d1 = {0.f, 0.f, 0.f, 0.f};
            float4 d2 = {0.f, 0.f, 0.f, 0.f}, d3 = {0.f, 0.f, 0.f, 0.f};
            float4 d4 = {0.f, 0.f, 0.f, 0.f}, d5 = {0.f, 0.f, 0.f, 0.f};
            float4 d6 = {0.f, 0.f, 0.f, 0.f}, d7 = {0.f, 0.f, 0.f, 0.f};
#pragma unroll
            for (int rc = 0; rc < 4; ++rc) {
                const int c = kl * 4 + rc;
                LDA(0) LDA(1) LDA(2) LDA(3) LDA(4) LDA(5) LDA(6) LDA(7)
                LDB(0) LDB(1) LDB(2) LDB(3)
                ROWU(0) ROWU(1) ROWU(2) ROWU(3)
                ROWU(4) ROWU(5) ROWU(6) ROWU(7)
            }
            const float4 si0 = *(const float4*)&sqs[0][kl][ty * 8];
            const float4 si1 = *(const float4*)&sqs[0][kl][ty * 8 + 4];
            const float4 sj4 = *(const float4*)&sqs[1][kl][tx * 4];
            EPIROW(0, si0.x)
            EPIROW(1, si0.y)
            EPIROW(2, si0.z)
            EPIROW(3, si0.w)
            EPIROW(4, si1.x)
            EPIROW(5, si1.y)
            EPIROW(6, si1.z)
            EPIROW(7, si1.w)
        }
    }

    // ---- stores: direct + mirrored (A exactly symmetric) ----
#pragma unroll
    for (int u = 0; u < 8; ++u) {
        unsigned m4 = (fail >> (u * 4)) & 0xfu;
        float4 o;
        o.x = (m4 & 1u) ? 0.0f : 1.0f;
        o.y = (m4 & 2u) ? 0.0f : 1.0f;
        o.z = (m4 & 4u) ? 0.0f : 1.0f;
        o.w = (m4 & 8u) ? 0.0f : 1.0f;
        *(float4*)&A[(size_t)(i0 + ty * 8 + u) * NPATCH + j0 + tx * 4] = o;
    }
    if (bi != bj) {
#pragma unroll
        for (int v = 0; v < 4; ++v) {
            float4 o0, o1;
            o0.x = ((fail >> (0 * 4 + v)) & 1u) ? 0.0f : 1.0f;
            o0.y = ((fail >> (1 * 4 + v)) & 1u) ? 0.0f : 1.0f;
            o0.z = ((fail >> (2 * 4 + v)) & 1u) ? 0.0f : 1.0f;
            o0.w = ((fail >> (3 * 4 + v)) & 1u) ? 0.0f : 1.0f;
            o1.x = ((fail >> (4 * 4 + v)) & 1u) ? 0.0f : 1.0f;
            o1.y = ((fail >> (5 * 4 + v)) & 1u) ? 0.0f : 1.0f;
            o1.z = ((fail >> (6 * 4 + v)) & 1u) ? 0.0f : 1.0f;
            o1.w = ((fail >> (7 * 4 + v)) & 1u) ? 0.0f : 1.0f;
            size_t base = (size_t)(j0 + tx * 4 + v) * NPATCH + i0 + ty * 8;
            *(float4*)&A[base] = o0;
            *(float4*)&A[base + 4] = o1;
        }
    }
}

extern "C" void kernel_launch(void* const* d_in, const int* in_sizes, int n_in,
                              void* d_out, int out_size, void* d_ws, size_t ws_size,
                              hipStream_t stream) {
    const float* x = (const float*)d_in[0];
    float* A = (float*)d_out;
    (void)d_ws; (void)ws_size;

    const int nblk = NT * (NT + 1) / 2;  // 528
    adj_kernel<<<nblk, 512, 0, stream>>>(x, A);
}